// Round 2
// baseline (58.943 us; speedup 1.0000x reference)
//
#include <hip/hip_runtime.h>
#include <hip/hip_bf16.h>

// Problem constants
#define SB 2      // batch
#define SS 256    // seq
#define SDM 512   // d_model
#define SH 8      // heads
#define LN_EPS 1e-5f

// Scratch layout (floats), placed inside d_out's attn_out region (starts at
// d_out + 262144, length 1,048,576 floats = 4MB):
//   F   : [which=2][b=2][g=4][cc=4][512]   = 32768 floats
//   Dt  : [b=2][gq=4][gk=4][cc=4][cs=8]    = 1024 floats
//   SFK : [b=2][c=32][d=64]                = 4096 floats
//   ctx : [b*256+q][512]                   = 262144 floats
// Total 300,032 floats < 1,048,576. The fill kernel overwrites it all with 1.0
// at the end (attn.sum(axis=-1) == 1 identically).

__device__ __forceinline__ bool sniff_mask_bytes(const unsigned int* m) {
    unsigned int acc = 0;
#pragma unroll
    for (int i = 0; i < 16; ++i) acc |= m[i];
    return acc > 1u;   // int32 mask words are 0/1; byte mask packs 4 bytes/word
}

// K1: compute the 16 needed "flat rows" (512 floats each) of projected Q and K
// per batch.  F[which][b][g][cc][cs*64+d] = P[b, s_i(cc,cs), h_i(g,cc)*64+d]
//   s_i = (cc<2 ? 240+8*cc : 8*(cc-2)) + cs,  h_i = g*2 + (cc>>1)
__global__ void k1_proj(const float* __restrict__ Qin, const float* __restrict__ Kin,
                        const float* __restrict__ WQ, const float* __restrict__ bQ,
                        const float* __restrict__ WK, const float* __restrict__ bK,
                        float* __restrict__ F) {
    int blk = blockIdx.x;                 // 64 blocks
    int b = blk & 1, which = (blk >> 1) & 1, r = blk >> 2;  // r in [0,16)
    int g = r >> 2, cc = r & 3;
    const float* In   = which ? Kin : Qin;
    const float* W    = which ? WK  : WQ;
    const float* bias = which ? bK  : bQ;
    int sbase = (cc < 2) ? (240 + 8 * cc) : (8 * (cc - 2));
    int h_i = g * 2 + (cc >> 1);

    __shared__ float in_l[8][512];
    int t = threadIdx.x;                  // 256 threads
#pragma unroll
    for (int ii = 0; ii < 16; ++ii) {
        int u = ii * 256 + t;
        in_l[u >> 9][u & 511] = In[(b * 256 + sbase + (u >> 9)) * 512 + (u & 511)];
    }
    __syncthreads();

    int d = t & 63, cs1 = t >> 6;         // this thread: (cs1, d) and (cs1+4, d)
    int n = h_i * 64 + d;
    float acc1 = 0.f, acc2 = 0.f;
    for (int m = 0; m < 512; ++m) {
        float w = W[m * 512 + n];
        acc1 += in_l[cs1][m] * w;
        acc2 += in_l[cs1 + 4][m] * w;
    }
    float bb = bias[n];
    int fb = (((which * 2 + b) * 4 + g) * 4 + cc) * 512;
    F[fb + cs1 * 64 + d]       = acc1 + bb;
    F[fb + (cs1 + 4) * 64 + d] = acc2 + bb;
}

// K2: D[b][gq][gk][cc][cs] = dot64(Fq[b][gq][cc][cs*64..], Fk[b][gk][cc][cs*64..]) / 8
__global__ void k2_dtab(const float* __restrict__ F, float* __restrict__ Dt) {
    int e = blockIdx.x * 256 + threadIdx.x;     // 1024 entries
    int cs = e & 7, cc = (e >> 3) & 3, gk = (e >> 5) & 3, gq = (e >> 7) & 3, b = (e >> 9) & 1;
    const float* fq = F + ((((0 * 2 + b) * 4 + gq) * 4 + cc) * 512) + cs * 64;
    const float* fk = F + ((((1 * 2 + b) * 4 + gk) * 4 + cc) * 512) + cs * 64;
    float acc = 0.f;
#pragma unroll
    for (int d = 0; d < 64; ++d) acc += fq[d] * fk[d];
    Dt[e] = acc * 0.125f;
}

// K2b: SFK[b][c][d] = sum_gv FK[b][gv][c>>3][(c&7)*64+d]
// (U[b,h,c,d] = 32*SFK: up/low validity windows are exactly complementary, so
// each (gv,c,t) pair contributes exactly one valid copy of the same flat row.)
__global__ void k2b_sfk(const float* __restrict__ F, float* __restrict__ SFK) {
    int e = blockIdx.x * 256 + threadIdx.x;     // 4096 entries
    int d = e & 63, c = (e >> 6) & 31, b = e >> 11;
    float acc = 0.f;
#pragma unroll
    for (int gv = 0; gv < 4; ++gv)
        acc += F[(((2 + b) * 4 + gv) * 4 + (c >> 3)) * 512 + (c & 7) * 64 + d];
    SFK[e] = acc;
}

// K3: per (b,h,q): loop k, build 32 scores from D + validity gates, softmax over c,
// A[c] += attn weight (UNGATED, summed over all k); then
// context[d] = 32 * sum_c A[c] * SFK[b][c][d].
__global__ void k3_attn(const float* __restrict__ Dt, const void* __restrict__ maskp,
                        const float* __restrict__ SFK, float* __restrict__ ctx) {
    int blk = blockIdx.x;                       // 1024 blocks
    int qb = blk & 63, h = (blk >> 6) & 7, b = blk >> 9;
    int t = threadIdx.x, wave = t >> 6, l = t & 63;
    int q = qb * 4 + wave;

    bool mbytes = sniff_mask_bytes((const unsigned int*)maskp);

    // Q-side validity per cc
    int i_q = h * 32 + (q >> 3);
    int g_q = q & 3;
    bool up_q = (q & 4) == 0;
    bool vq[4];
#pragma unroll
    for (int cc = 0; cc < 4; ++cc) {
        int row = g_q * 64 + 30 + cc;
        vq[cc] = up_q ? (i_q >= 256 - row) : (i_q <= 255 - row);
    }

    int ak = l & 3;                             // this lane's k-group
    const float* Db = Dt + ((b * 4 + g_q) * 4 + ak) * 32;
    float sq[32];
#pragma unroll
    for (int j = 0; j < 32; ++j) sq[j] = vq[j >> 3] ? Db[j] : 0.f;

    float A[32];
#pragma unroll
    for (int j = 0; j < 32; ++j) A[j] = 0.f;

    bool up_k = (l & 4) == 0;
    for (int r = 0; r < 4; ++r) {
        int k = r * 64 + l;
        int i_k = h * 32 + (k >> 3);
        bool vk[4];
#pragma unroll
        for (int cc = 0; cc < 4; ++cc) {
            int row = ak * 64 + 30 + cc;
            vk[cc] = up_k ? (i_k >= 256 - row) : (i_k <= 255 - row);
        }
        int midx = (b * 256 + q) * 256 + k;
        bool masked = mbytes ? (((const unsigned char*)maskp)[midx] != 0)
                             : (((const int*)maskp)[midx] != 0);
        if (masked) {
            // scores all -1e9 -> softmax exactly uniform 1/32
#pragma unroll
            for (int j = 0; j < 32; ++j) A[j] += 0.03125f;
        } else {
            float s[32];
            float mx = -1e30f;
#pragma unroll
            for (int j = 0; j < 32; ++j) {
                s[j] = vk[j >> 3] ? sq[j] : 0.f;
                mx = fmaxf(mx, s[j]);
            }
            float den = 0.f;
#pragma unroll
            for (int j = 0; j < 32; ++j) {
                s[j] = __expf(s[j] - mx);
                den += s[j];
            }
            float inv = 1.0f / den;
#pragma unroll
            for (int j = 0; j < 32; ++j) A[j] += s[j] * inv;
        }
    }

    // full 64-lane butterfly: A[j] = sum over all k of attn[q,k,j]
#pragma unroll
    for (int off = 1; off < 64; off <<= 1) {
#pragma unroll
        for (int j = 0; j < 32; ++j) A[j] += __shfl_xor(A[j], off);
    }

    // context[d=l] = 32 * sum_c A[c] * SFK[b][c][l]
    const float* S = SFK + b * 2048;
    float acc = 0.f;
#pragma unroll
    for (int j = 0; j < 32; ++j) acc += A[j] * S[j * 64 + l];
    ctx[(b * 256 + q) * 512 + h * 64 + l] = 32.f * acc;
}

// K4: out = ctx @ Wo + bo + Q, then LayerNorm -> y_n (first 262144 floats of d_out)
__global__ void k4_outln(const float* __restrict__ ctx, const float* __restrict__ Wo,
                         const float* __restrict__ bo, const float* __restrict__ Qin,
                         const float* __restrict__ gamma, const float* __restrict__ beta,
                         float* __restrict__ out) {
    int blk = blockIdx.x;        // 128 blocks, 4 rows each
    int rho0 = blk * 4;          // global row = b*256+q
    int t = threadIdx.x;         // 512 threads = one column each

    __shared__ float ctx_lt[512][4];  // transposed stage: [m][r]
#pragma unroll
    for (int r = 0; r < 4; ++r) ctx_lt[t][r] = ctx[(rho0 + r) * 512 + t];
    __syncthreads();

    float a0 = 0.f, a1 = 0.f, a2 = 0.f, a3 = 0.f;
    for (int m = 0; m < 512; ++m) {
        float w = Wo[m * 512 + t];
        float4 x = *(const float4*)&ctx_lt[m][0];
        a0 += x.x * w; a1 += x.y * w; a2 += x.z * w; a3 += x.w * w;
    }
    float bb = bo[t];
    float y[4];
    y[0] = a0 + bb + Qin[(rho0 + 0) * 512 + t];
    y[1] = a1 + bb + Qin[(rho0 + 1) * 512 + t];
    y[2] = a2 + bb + Qin[(rho0 + 2) * 512 + t];
    y[3] = a3 + bb + Qin[(rho0 + 3) * 512 + t];

    // row-wise LayerNorm over 512 columns (8 waves)
    float sy[4], sy2[4];
#pragma unroll
    for (int r = 0; r < 4; ++r) { sy[r] = y[r]; sy2[r] = y[r] * y[r]; }
#pragma unroll
    for (int off = 1; off < 64; off <<= 1) {
#pragma unroll
        for (int r = 0; r < 4; ++r) {
            sy[r]  += __shfl_xor(sy[r],  off);
            sy2[r] += __shfl_xor(sy2[r], off);
        }
    }
    __shared__ float red[8][4][2];
    int wv = t >> 6, l = t & 63;
    if (l == 0) {
#pragma unroll
        for (int r = 0; r < 4; ++r) { red[wv][r][0] = sy[r]; red[wv][r][1] = sy2[r]; }
    }
    __syncthreads();
    __shared__ float mrs[4][2];
    if (t < 4) {
        float s1 = 0.f, s2 = 0.f;
#pragma unroll
        for (int w = 0; w < 8; ++w) { s1 += red[w][t][0]; s2 += red[w][t][1]; }
        float mu  = s1 * (1.f / 512.f);
        float var = s2 * (1.f / 512.f) - mu * mu;
        mrs[t][0] = mu;
        mrs[t][1] = rsqrtf(var + LN_EPS);
    }
    __syncthreads();
    float gm = gamma[t], bt = beta[t];
#pragma unroll
    for (int r = 0; r < 4; ++r) {
        out[(rho0 + r) * 512 + t] = (y[r] - mrs[r][0]) * mrs[r][1] * gm + bt;
    }
}

// K5: attn_out = softmax(...,axis=-1).sum(axis=-1) == 1.0 identically.
// Also overwrites the scratch (F/Dt/SFK/ctx) which lives in this region.
__global__ void k5_fill(float* __restrict__ p, int n) {
    int i = (blockIdx.x * 256 + threadIdx.x) * 4;
    float4 one = make_float4(1.f, 1.f, 1.f, 1.f);
    for (; i < n; i += gridDim.x * 256 * 4) *(float4*)(p + i) = one;
}

extern "C" void kernel_launch(void* const* d_in, const int* in_sizes, int n_in,
                              void* d_out, int out_size, void* d_ws, size_t ws_size,
                              hipStream_t stream) {
    (void)in_sizes; (void)n_in; (void)out_size; (void)d_ws; (void)ws_size;
    const float* Qin  = (const float*)d_in[0];
    const float* Kin  = (const float*)d_in[1];
    /* V = d_in[2] unused (reference deletes v_s) */
    const void*  mask = d_in[3];
    const float* WQ   = (const float*)d_in[4];
    const float* bQ   = (const float*)d_in[5];
    const float* WK   = (const float*)d_in[6];
    const float* bK   = (const float*)d_in[7];
    /* WV = d_in[8], bV = d_in[9] unused */
    const float* Wo   = (const float*)d_in[10];
    const float* bo   = (const float*)d_in[11];
    const float* gamma= (const float*)d_in[12];
    const float* beta = (const float*)d_in[13];

    float* out     = (float*)d_out;
    float* scratch = out + 262144;          // attn_out region (1,048,576 floats)
    float* F       = scratch;               // 32768 floats
    float* Dt      = scratch + 32768;       // 1024 floats
    float* SFK     = scratch + 33792;       // 4096 floats
    float* ctx     = scratch + 37888;       // 262144 floats

    k1_proj <<<dim3(64),   dim3(256), 0, stream>>>(Qin, Kin, WQ, bQ, WK, bK, F);
    k2_dtab <<<dim3(4),    dim3(256), 0, stream>>>(F, Dt);
    k2b_sfk <<<dim3(16),   dim3(256), 0, stream>>>(F, SFK);
    k3_attn <<<dim3(1024), dim3(256), 0, stream>>>(Dt, mask, SFK, ctx);
    k4_outln<<<dim3(128),  dim3(512), 0, stream>>>(ctx, Wo, bo, Qin, gamma, beta, out);
    k5_fill <<<dim3(256),  dim3(256), 0, stream>>>(scratch, 1048576);
}

// Round 3
// 45.911 us; speedup vs baseline: 1.2839x; 1.2839x over previous
//
#include <hip/hip_runtime.h>
#include <hip/hip_bf16.h>

#define LN_EPS 1e-5f

// ---------------------------------------------------------------------------
// Index algebra (derived from the reference's reshape chain, verified passing):
//   F[which][b][g][cc][cs*64+d] = P_{which}[b, s_i, h_i*64+d] + bias
//     s_i = (cc<2 ? 240+8*cc : 8*(cc-2)) + cs,  h_i = g*2 + (cc>>1)
//   Dt[b][gq][gk][cc][cs] = dot64(Fq, Fk) / 8
//   SFK[b][c][d] = sum_gv FK[b][gv][c>>3][(c&7)*64+d]   (U = 32*SFK)
//   attn_out == 1.0 everywhere.
// ---------------------------------------------------------------------------

__device__ __forceinline__ bool sniff_mask_bytes(const unsigned int* m) {
    unsigned int acc = 0;
#pragma unroll
    for (int i = 0; i < 16; ++i) acc |= m[i];
    return acc > 1u;   // int32 mask words are 0/1; byte mask packs 4 bytes/word
}

// kA: projection GEMM, split-K.  Ppart[kc][f] = partial dot over m in [kc*64, kc*64+64)
// grid: 512 blocks = kc(8) x which(2) x b(2) x g(4) x cc(4); 512 threads = cs(8) x d(64)
__global__ void kA_proj_part(const float* __restrict__ Qin, const float* __restrict__ Kin,
                             const float* __restrict__ WQ, const float* __restrict__ WK,
                             float* __restrict__ Ppart) {
    int bx = blockIdx.x;
    int cc = bx & 3, g = (bx >> 2) & 3, b = (bx >> 4) & 1, which = (bx >> 5) & 1, kc = bx >> 6;
    int t = threadIdx.x, d = t & 63, cs = t >> 6;

    const float* In = which ? Kin : Qin;
    const float* W  = which ? WK  : WQ;
    int sbase = (cc < 2) ? (240 + 8 * cc) : (8 * (cc - 2));
    int s_i = sbase + cs;
    int n = (g * 2 + (cc >> 1)) * 64 + d;

    const float* xrow = In + (b * 256 + s_i) * 512 + kc * 64;
    const float* wcol = W + (kc * 64) * 512 + n;
    float acc = 0.f;
#pragma unroll
    for (int m = 0; m < 64; ++m) acc += xrow[m] * wcol[m * 512];

    int fsub = (((which * 2 + b) * 4 + g) * 4 + cc) * 512 + cs * 64 + d;
    Ppart[kc * 32768 + fsub] = acc;
}

// kB: F[f] = sum_kc Ppart[kc][f] + bias.  128 blocks x 256 threads.
__global__ void kB_proj_red(const float* __restrict__ Ppart,
                            const float* __restrict__ bQ, const float* __restrict__ bK,
                            float* __restrict__ F) {
    int f = blockIdx.x * 256 + threadIdx.x;
    float acc = 0.f;
#pragma unroll
    for (int kc = 0; kc < 8; ++kc) acc += Ppart[kc * 32768 + f];
    int which = f >> 14, cc = (f >> 9) & 3, g = (f >> 11) & 3, d = f & 63;
    int n = (g * 2 + (cc >> 1)) * 64 + d;
    F[f] = acc + (which ? bK[n] : bQ[n]);
}

// kC: Dt (8 lanes per entry, shfl reduce) then SFK.  48 blocks x 256 threads.
// slots [0, 8192): Dt;  slots [8192, 12288): SFK
__global__ void kC_dtab_sfk(const float* __restrict__ F, float* __restrict__ Dt,
                            float* __restrict__ SFK) {
    int slot = blockIdx.x * 256 + threadIdx.x;
    if (slot < 8192) {
        int part = slot & 7, e = slot >> 3;
        int cs = e & 7, cc = (e >> 3) & 3, gk = (e >> 5) & 3, gq = (e >> 7) & 3, b = (e >> 9) & 1;
        const float* fq = F + ((((0 * 2 + b) * 4 + gq) * 4 + cc) * 512) + cs * 64 + part * 8;
        const float* fk = F + ((((1 * 2 + b) * 4 + gk) * 4 + cc) * 512) + cs * 64 + part * 8;
        float acc = 0.f;
#pragma unroll
        for (int u = 0; u < 8; ++u) acc += fq[u] * fk[u];
        acc += __shfl_xor(acc, 1);
        acc += __shfl_xor(acc, 2);
        acc += __shfl_xor(acc, 4);
        if (part == 0) Dt[e] = acc * 0.125f;
    } else {
        int e = slot - 8192;
        int d = e & 63, c = (e >> 6) & 31, b = e >> 11;
        float acc = 0.f;
#pragma unroll
        for (int gv = 0; gv < 4; ++gv)
            acc += F[(((2 + b) * 4 + gv) * 4 + (c >> 3)) * 512 + (c & 7) * 64 + d];
        SFK[e] = acc;
    }
}

// k3: per (b,h,q): loop k, softmax over c (with mask->uniform shortcut),
// A[c] summed over ALL k; ctx[d] = 32 * sum_c A[c]*SFK[b][c][d].
// Optionally fills the attn_out region with 1.0 (fill != 0).
__global__ void k3_attn(const float* __restrict__ Dt, const void* __restrict__ maskp,
                        const float* __restrict__ SFK, float* __restrict__ ctx,
                        float* __restrict__ attnp, int fill) {
    int blk = blockIdx.x;                       // 1024 blocks
    int t = threadIdx.x;
    if (fill) {
        float4 one = make_float4(1.f, 1.f, 1.f, 1.f);
        ((float4*)attnp)[blk * 256 + t] = one;
    }
    int qb = blk & 63, h = (blk >> 6) & 7, b = blk >> 9;
    int wave = t >> 6, l = t & 63;
    int q = qb * 4 + wave;

    bool mbytes = sniff_mask_bytes((const unsigned int*)maskp);

    int i_q = h * 32 + (q >> 3);
    int g_q = q & 3;
    bool up_q = (q & 4) == 0;
    bool vq[4];
#pragma unroll
    for (int cc = 0; cc < 4; ++cc) {
        int row = g_q * 64 + 30 + cc;
        vq[cc] = up_q ? (i_q >= 256 - row) : (i_q <= 255 - row);
    }

    int ak = l & 3;
    const float* Db = Dt + ((b * 4 + g_q) * 4 + ak) * 32;
    float sq[32];
#pragma unroll
    for (int j = 0; j < 32; ++j) sq[j] = vq[j >> 3] ? Db[j] : 0.f;

    float A[32];
#pragma unroll
    for (int j = 0; j < 32; ++j) A[j] = 0.f;

    bool up_k = (l & 4) == 0;
    for (int r = 0; r < 4; ++r) {
        int k = r * 64 + l;
        int i_k = h * 32 + (k >> 3);
        bool vk[4];
#pragma unroll
        for (int cc = 0; cc < 4; ++cc) {
            int row = ak * 64 + 30 + cc;
            vk[cc] = up_k ? (i_k >= 256 - row) : (i_k <= 255 - row);
        }
        int midx = (b * 256 + q) * 256 + k;
        bool masked = mbytes ? (((const unsigned char*)maskp)[midx] != 0)
                             : (((const int*)maskp)[midx] != 0);
        if (masked) {
#pragma unroll
            for (int j = 0; j < 32; ++j) A[j] += 0.03125f;
        } else {
            float s[32];
            float mx = -1e30f;
#pragma unroll
            for (int j = 0; j < 32; ++j) {
                s[j] = vk[j >> 3] ? sq[j] : 0.f;
                mx = fmaxf(mx, s[j]);
            }
            float den = 0.f;
#pragma unroll
            for (int j = 0; j < 32; ++j) {
                s[j] = __expf(s[j] - mx);
                den += s[j];
            }
            float inv = 1.0f / den;
#pragma unroll
            for (int j = 0; j < 32; ++j) A[j] += s[j] * inv;
        }
    }

#pragma unroll
    for (int off = 1; off < 64; off <<= 1) {
#pragma unroll
        for (int j = 0; j < 32; ++j) A[j] += __shfl_xor(A[j], off);
    }

    const float* S = SFK + b * 2048;
    float acc = 0.f;
#pragma unroll
    for (int j = 0; j < 32; ++j) acc += A[j] * S[j * 64 + l];
    ctx[(b * 256 + q) * 512 + h * 64 + l] = 32.f * acc;
}

// k4a: ctx @ Wo, split-K.  grid = kc(NC) x rowoct(64), 512 threads (one col each,
// 8 rows).  CL = 512/NC.
__global__ void k4a_wo_part(const float* __restrict__ ctx, const float* __restrict__ Wo,
                            float* __restrict__ Wpart, int CL) {
    int bx = blockIdx.x;
    int ro = bx & 63, kc = bx >> 6;
    int t = threadIdx.x;

    __shared__ float ctx_l[256][8];             // [j][r], j < CL
    int iters = CL >> 6;                        // CL*8/512
    for (int ii = 0; ii < iters; ++ii) {
        int idx = ii * 512 + t;
        int j = idx >> 3, r = idx & 7;
        ctx_l[j][r] = ctx[(ro * 8 + r) * 512 + kc * CL + j];
    }
    __syncthreads();

    float acc[8];
#pragma unroll
    for (int r = 0; r < 8; ++r) acc[r] = 0.f;
#pragma unroll 8
    for (int j = 0; j < CL; ++j) {
        float w = Wo[(kc * CL + j) * 512 + t];
#pragma unroll
        for (int r = 0; r < 8; ++r) acc[r] += ctx_l[j][r] * w;
    }
#pragma unroll
    for (int r = 0; r < 8; ++r)
        Wpart[(kc * 512 + ro * 8 + r) * 512 + t] = acc[r];
}

// k4b: reduce partials + bias + residual, LayerNorm.  128 blocks x 512 threads.
__global__ void k4b_ln(const float* __restrict__ Wpart, const float* __restrict__ bo,
                       const float* __restrict__ Qin, const float* __restrict__ gamma,
                       const float* __restrict__ beta, float* __restrict__ out, int NC) {
    int rho0 = blockIdx.x * 4;
    int t = threadIdx.x;

    float bb = bo[t];
    float y[4];
#pragma unroll
    for (int r = 0; r < 4; ++r) {
        float a = 0.f;
        for (int kc = 0; kc < NC; ++kc) a += Wpart[(kc * 512 + rho0 + r) * 512 + t];
        y[r] = a + bb + Qin[(rho0 + r) * 512 + t];
    }

    float sy[4], sy2[4];
#pragma unroll
    for (int r = 0; r < 4; ++r) { sy[r] = y[r]; sy2[r] = y[r] * y[r]; }
#pragma unroll
    for (int off = 1; off < 64; off <<= 1) {
#pragma unroll
        for (int r = 0; r < 4; ++r) {
            sy[r]  += __shfl_xor(sy[r],  off);
            sy2[r] += __shfl_xor(sy2[r], off);
        }
    }
    __shared__ float red[8][4][2];
    int wv = t >> 6, l = t & 63;
    if (l == 0) {
#pragma unroll
        for (int r = 0; r < 4; ++r) { red[wv][r][0] = sy[r]; red[wv][r][1] = sy2[r]; }
    }
    __syncthreads();
    __shared__ float mrs[4][2];
    if (t < 4) {
        float s1 = 0.f, s2 = 0.f;
#pragma unroll
        for (int w = 0; w < 8; ++w) { s1 += red[w][t][0]; s2 += red[w][t][1]; }
        float mu  = s1 * (1.f / 512.f);
        float var = s2 * (1.f / 512.f) - mu * mu;
        mrs[t][0] = mu;
        mrs[t][1] = rsqrtf(var + LN_EPS);
    }
    __syncthreads();
    float gm = gamma[t], bt = beta[t];
#pragma unroll
    for (int r = 0; r < 4; ++r) {
        out[(rho0 + r) * 512 + t] = (y[r] - mrs[r][0]) * mrs[r][1] * gm + bt;
    }
}

// k5 (fallback plan only): fill attn_out region (which hosted scratch) with 1.0
__global__ void k5_fill(float* __restrict__ p, int n) {
    int i = (blockIdx.x * 256 + threadIdx.x) * 4;
    float4 one = make_float4(1.f, 1.f, 1.f, 1.f);
    for (; i < n; i += gridDim.x * 256 * 4) *(float4*)(p + i) = one;
}

extern "C" void kernel_launch(void* const* d_in, const int* in_sizes, int n_in,
                              void* d_out, int out_size, void* d_ws, size_t ws_size,
                              hipStream_t stream) {
    (void)in_sizes; (void)n_in; (void)out_size;
    const float* Qin  = (const float*)d_in[0];
    const float* Kin  = (const float*)d_in[1];
    const void*  mask = d_in[3];
    const float* WQ   = (const float*)d_in[4];
    const float* bQ   = (const float*)d_in[5];
    const float* WK   = (const float*)d_in[6];
    const float* bK   = (const float*)d_in[7];
    const float* Wo   = (const float*)d_in[10];
    const float* bo   = (const float*)d_in[11];
    const float* gamma= (const float*)d_in[12];
    const float* beta = (const float*)d_in[13];

    float* out   = (float*)d_out;
    float* attnp = out + 262144;                 // 1,048,576 floats of output 1

    const size_t NEED = 1610752ull * 4ull;       // plan-A scratch bytes
    if (ws_size >= NEED) {
        // Plan A: scratch fully in d_ws; attn_out filled by k3.
        float* ws    = (float*)d_ws;
        float* Ppart = ws;                       // 262144
        float* F     = ws + 262144;              // 32768
        float* Dt    = ws + 294912;              // 1024
        float* SFK   = ws + 295936;              // 4096
        float* ctx   = ws + 300032;              // 262144
        float* Wpart = ws + 562176;              // 4*262144
        const int NC = 4, CL = 128;

        kA_proj_part<<<dim3(512),     dim3(512), 0, stream>>>(Qin, Kin, WQ, WK, Ppart);
        kB_proj_red <<<dim3(128),     dim3(256), 0, stream>>>(Ppart, bQ, bK, F);
        kC_dtab_sfk <<<dim3(48),      dim3(256), 0, stream>>>(F, Dt, SFK);
        k3_attn     <<<dim3(1024),    dim3(256), 0, stream>>>(Dt, mask, SFK, ctx, attnp, 1);
        k4a_wo_part <<<dim3(64 * NC), dim3(512), 0, stream>>>(ctx, Wo, Wpart, CL);
        k4b_ln      <<<dim3(128),     dim3(512), 0, stream>>>(Wpart, bo, Qin, gamma, beta, out, NC);
    } else {
        // Plan B: scratch inside the attn_out region (1,048,576 floats), NC=2,
        // Wpart overlaps the (dead) Ppart region; final fill restores ones.
        float* Ppart = attnp;                    // [0, 262144)
        float* F     = attnp + 524288;           // [524288, 557056)
        float* Dt    = attnp + 557056;           // [557056, 558080)
        float* SFK   = attnp + 558080;           // [558080, 562176)
        float* ctx   = attnp + 786432;           // [786432, 1048576)
        float* Wpart = attnp;                    // [0, 524288) — Ppart dead by k4a
        const int NC = 2, CL = 256;

        kA_proj_part<<<dim3(512),     dim3(512), 0, stream>>>(Qin, Kin, WQ, WK, Ppart);
        kB_proj_red <<<dim3(128),     dim3(256), 0, stream>>>(Ppart, bQ, bK, F);
        kC_dtab_sfk <<<dim3(48),      dim3(256), 0, stream>>>(F, Dt, SFK);
        k3_attn     <<<dim3(1024),    dim3(256), 0, stream>>>(Dt, mask, SFK, ctx, attnp, 0);
        k4a_wo_part <<<dim3(64 * NC), dim3(512), 0, stream>>>(ctx, Wo, Wpart, CL);
        k4b_ln      <<<dim3(128),     dim3(512), 0, stream>>>(Wpart, bo, Qin, gamma, beta, out, NC);
        k5_fill     <<<dim3(256),     dim3(256), 0, stream>>>(attnp, 1048576);
    }
}